// Round 7
// baseline (251.497 us; speedup 1.0000x reference)
//
#include <hip/hip_runtime.h>

// out[b, j] = p_cls[b, j>>8] * p_subcls[b, j>>6] * p_maingrp[b, j>>5]
//           * p_subgrp[b, j>>3] * p_fi[b, j]
// Memory-bound streaming multiply (~292 MB demand, ~216 MB HBM after L3).
// R2 (grid-stride, per-iter drain): 86 us, 2.5 TB/s. R4 (one-shot, batched
// loads): ~81 us — neutral. Both keep only one load-generation in flight per
// wave. This version: each wave holds FOUR independent rows' loads in flight
// (load phase fully unrolled, then store phase) — ~9 KB outstanding reads per
// wave, no vmcnt(0) drain between rows. Static indexing only (no scratch).

typedef float f32x4 __attribute__((ext_vector_type(4)));

#define ROWS_PER_BLOCK 4

__global__ __launch_bounds__(256) void hier_mul_kernel(
        const float* __restrict__ p_cls,      // [B, 8]
        const float* __restrict__ p_subcls,   // [B, 32]
        const float* __restrict__ p_maingrp,  // [B, 64]
        const float* __restrict__ p_subgrp,   // [B, 256]
        const float* __restrict__ p_fi,       // [B, 2048]
        float* __restrict__ out) {            // [B, 2048]
    const int t    = threadIdx.x;             // subgroup index 0..255
    const int row0 = blockIdx.x * ROWS_PER_BLOCK;

    const f32x4* __restrict__ fi4 = reinterpret_cast<const f32x4*>(p_fi);
    f32x4* out4 = reinterpret_cast<f32x4*>(out);

    f32x4 a[ROWS_PER_BLOCK], b[ROWS_PER_BLOCK];
    float s[ROWS_PER_BLOCK];

    // Phase 1: issue ALL loads for 4 rows back-to-back (independent).
#pragma unroll
    for (int u = 0; u < ROWS_PER_BLOCK; ++u) {
        const int row = row0 + u;
        const int i0  = (row << 9) + (t << 1);   // 2 float4 = 8 leaves/thread
        a[u] = fi4[i0];
        b[u] = fi4[i0 + 1];
        s[u] = p_cls    [(row << 3) + (t >> 5)]   // wave-broadcast
             * p_subcls [(row << 5) + (t >> 3)]   // 8 distinct/wave
             * p_maingrp[(row << 6) + (t >> 2)]   // 16 distinct/wave
             * p_subgrp [(row << 8) + t];         // coalesced
    }

    // Phase 2: multiply + store (waits are counted vmcnt, not full drains).
#pragma unroll
    for (int u = 0; u < ROWS_PER_BLOCK; ++u) {
        const int i0 = ((row0 + u) << 9) + (t << 1);
        out4[i0]     = a[u] * s[u];
        out4[i0 + 1] = b[u] * s[u];
    }
}

extern "C" void kernel_launch(void* const* d_in, const int* in_sizes, int n_in,
                              void* d_out, int out_size, void* d_ws, size_t ws_size,
                              hipStream_t stream) {
    const float* p_cls     = (const float*)d_in[0];
    const float* p_subcls  = (const float*)d_in[1];
    const float* p_maingrp = (const float*)d_in[2];
    const float* p_subgrp  = (const float*)d_in[3];
    const float* p_fi      = (const float*)d_in[4];
    float* out = (float*)d_out;

    const int rows = in_sizes[4] / 2048;          // B = 16384
    const int grid = rows / ROWS_PER_BLOCK;       // 4096 blocks
    hier_mul_kernel<<<grid, 256, 0, stream>>>(
        p_cls, p_subcls, p_maingrp, p_subgrp, p_fi, out);
}